// Round 5
// baseline (340.569 us; speedup 1.0000x reference)
//
#include <hip/hip_runtime.h>
#include <hip/hip_bf16.h>

#define D_DIM 128
#define TILE 128

typedef __attribute__((ext_vector_type(8))) short short8;   // 8 bf16 in 4 VGPRs (MFMA A/B frag)
typedef __attribute__((ext_vector_type(4))) float floatx4;  // MFMA C/D frag

// ---------------------------------------------------------------------------
// prep: round fp32 rows to bf16 (stored to ws) and compute row sum-of-squares
// of the ROUNDED values (so d2 = ||a_hat - b_hat||^2 >= 0 exactly).
// ---------------------------------------------------------------------------
__global__ void prep_kernel(const float* __restrict__ za, const float* __restrict__ zb,
                            __hip_bfloat16* __restrict__ abf, __hip_bfloat16* __restrict__ bbf,
                            float* __restrict__ a2, float* __restrict__ b2, int N) {
    int r = blockIdx.x * 4 + (threadIdx.x >> 6);
    int lane = threadIdx.x & 63;
    const float* src; __hip_bfloat16* dst; float* nrm; int row;
    if (r < N) { src = za; dst = abf; nrm = a2; row = r; }
    else       { src = zb; dst = bbf; nrm = b2; row = r - N; }
    const float2 v = ((const float2*)(src + (size_t)row * D_DIM))[lane];
    __hip_bfloat16 h0 = __float2bfloat16(v.x);
    __hip_bfloat16 h1 = __float2bfloat16(v.y);
    float f0 = __bfloat162float(h0), f1 = __bfloat162float(h1);
    float ss = f0 * f0 + f1 * f1;
    ushort2 st;
    st.x = *(const unsigned short*)&h0;
    st.y = *(const unsigned short*)&h1;
    ((ushort2*)(dst + (size_t)row * D_DIM))[lane] = st;
    #pragma unroll
    for (int off = 32; off; off >>= 1) ss += __shfl_down(ss, off, 64);
    if (lane == 0) nrm[row] = ss;
}

// ---------------------------------------------------------------------------
// dist v5: STRIP-PIPELINED, BARRIER-FREE.
// Ledger: input path (LDS vs L2-direct) null; store granule (64B vs 512B)
// null; occupancy 2->3 null; NT stores -54us. All bandwidth-side knobs are
// slack => the bottleneck is time-structure: the monolithic block (stage ->
// barrier -> all-MFMA -> all-sqrt -> all-store, 3 barriers) leaves the write
// pipe idle most of the block's life. v5 makes every wave an independent
// stream: preload n-side frags once, then 4 strips of
// {4 frag loads -> 16 MFMA -> 16 sqrt -> 4 stores}. Stores start ~1/4 into
// the block; no LDS, no barriers; 4 blocks/CU (16 waves/CU) interleave.
//
// Verified gfx950 layouts (learn_hip m89/m91), operand-swapped:
//   acc = mfma(afr from bbf (m rows), bfr from abf (n rows))
//   acc[jn][r] <-> m = colBase+wm+jm*16+(lane>>4)*4+r
//                  n = rowBase+wn+jn*16+(lane&15)
// ---------------------------------------------------------------------------
__global__ __launch_bounds__(256, 4)
void dist_kernel(const __hip_bfloat16* __restrict__ abf, const __hip_bfloat16* __restrict__ bbf,
                 const float* __restrict__ a2, const float* __restrict__ b2,
                 float* __restrict__ out, int M) {
    const int rowBase = blockIdx.y * TILE;   // n: into z_anc
    const int colBase = blockIdx.x * TILE;   // m: into z_pos_neg
    const int tid  = threadIdx.x;
    const int wave = tid >> 6;
    const int lane = tid & 63;
    const int wn = (wave >> 1) * 64;         // wave n-offset in tile
    const int wm = (wave & 1) * 64;          // wave m-offset in tile
    const int lrow = lane & 15;
    const int lk8  = (lane >> 4) * 8;
    const int mq   = (lane >> 4) * 4;

    // Preload the wave's n-side (B-operand) frags for ALL k-steps: 16 short8
    // = 64 VGPR. Reused by all 4 m-strips -> L2 read traffic same as R1.
    short8 bfr[4][4];   // [ks][jn]
    float an[4];
    size_t rowOff[4];
    #pragma unroll
    for (int jn = 0; jn < 4; ++jn) {
        const int n = rowBase + wn + jn * 16 + lrow;
        const int aOff = n * D_DIM + lk8;    // max 2^20: int safe
        #pragma unroll
        for (int ks = 0; ks < 4; ++ks)
            bfr[ks][jn] = *(const short8*)(abf + (aOff + ks * 32));
        an[jn] = a2[n];
        rowOff[jn] = (size_t)n * (size_t)M;
    }

    // 4 independent 16-m strips: compute -> finish -> store, no sync.
    #pragma unroll 1
    for (int jm = 0; jm < 4; ++jm) {
        const int m16 = colBase + wm + jm * 16;
        const int bOff = (m16 + lrow) * D_DIM + lk8;
        short8 afr[4];
        #pragma unroll
        for (int ks = 0; ks < 4; ++ks)
            afr[ks] = *(const short8*)(bbf + (bOff + ks * 32));

        floatx4 acc[4] = {};   // [jn]
        #pragma unroll
        for (int ks = 0; ks < 4; ++ks)
            #pragma unroll
            for (int jn = 0; jn < 4; ++jn)
                acc[jn] = __builtin_amdgcn_mfma_f32_16x16x32_bf16(afr[ks], bfr[ks][jn], acc[jn], 0, 0, 0);

        const floatx4 bq = *(const floatx4*)(b2 + m16 + mq);
        #pragma unroll
        for (int jn = 0; jn < 4; ++jn) {
            floatx4 v;
            #pragma unroll
            for (int r = 0; r < 4; ++r) {
                float d2 = an[jn] + bq[r] - 2.0f * acc[jn][r];
                d2 = fmaxf(d2, 0.0f);
                v[r] = -__builtin_amdgcn_sqrtf(d2);
            }
            *(floatx4*)(out + rowOff[jn] + m16 + mq) = v;
        }
    }
}

extern "C" void kernel_launch(void* const* d_in, const int* in_sizes, int n_in,
                              void* d_out, int out_size, void* d_ws, size_t ws_size,
                              hipStream_t stream) {
    const float* za = (const float*)d_in[0];
    const float* zb = (const float*)d_in[1];
    const int N = in_sizes[0] / D_DIM;   // 8192
    const int M = in_sizes[1] / D_DIM;   // 8192
    float* out = (float*)d_out;

    // workspace layout: abf [N*128 bf16] | bbf [M*128 bf16] | a2 [N f32] | b2 [M f32]
    char* ws = (char*)d_ws;
    __hip_bfloat16* abf = (__hip_bfloat16*)ws;
    __hip_bfloat16* bbf = (__hip_bfloat16*)(ws + (size_t)N * D_DIM * sizeof(__hip_bfloat16));
    float* a2 = (float*)(ws + (size_t)(N + M) * D_DIM * sizeof(__hip_bfloat16));
    float* b2 = a2 + N;

    prep_kernel<<<(N + M) / 4, 256, 0, stream>>>(za, zb, abf, bbf, a2, b2, N);

    dim3 grid(M / TILE, N / TILE);
    dist_kernel<<<grid, 256, 0, stream>>>(abf, bbf, a2, b2, out, M);
}